// Round 8
// baseline (415.209 us; speedup 1.0000x reference)
//
#include <hip/hip_runtime.h>
#include <stdint.h>

typedef unsigned short u16;
typedef __attribute__((ext_vector_type(8))) short short8;
typedef __attribute__((ext_vector_type(4))) float floatx4;

#define DH 128   // D = H*C
#define NH 4     // heads
#define CH 32    // channels per head

#define NPB  256   // nodes per bucket (dst >> 8) — dlocal fits 8 bits
#define MAXB 512   // max buckets (N <= 131072)
#define EPB 4096   // edges per block in binning passes (391 blocks: was 196)
#define SGRID 1024 // stats blocks

__device__ __forceinline__ float bf2f(u16 u) {
    union { unsigned int i; float f; } c; c.i = ((unsigned int)u) << 16; return c.f;
}
__device__ __forceinline__ u16 f2bf(float f) {
    union { float f; unsigned int i; } c; c.f = f;
    unsigned int x = c.i;
    x += 0x7FFFu + ((x >> 16) & 1u);   // round-to-nearest-even
    return (u16)(x >> 16);
}
// unpack a u32 holding two bf16 (lo = even channel, hi = odd channel)
__device__ __forceinline__ float b2f_lo(unsigned v) {
    union { unsigned u; float f; } c; c.u = v << 16; return c.f;
}
__device__ __forceinline__ float b2f_hi(unsigned v) {
    union { unsigned u; float f; } c; c.u = v & 0xffff0000u; return c.f;
}
// leaky_relu(x,0.2) branchless
__device__ __forceinline__ float lr(float x) { return fmaxf(x, 0.2f * x); }

// ---- repack [lin_w | gat_w] (f32) into MFMA B-fragment order (bf16) ------
__global__ void repack_w(const float* __restrict__ lin_w, const float* __restrict__ gat_w,
                         u16* __restrict__ wpack) {
    int t = blockIdx.x * blockDim.x + threadIdx.x;   // 0 .. 32767
    int j    = t & 7;
    int lane = (t >> 3) & 63;
    int ks   = (t >> 9) & 3;
    int ct   = t >> 11;
    int k    = ks * 32 + (lane >> 4) * 8 + j;
    int col  = ct * 16 + (lane & 15);
    float v = (col < DH) ? lin_w[k * DH + col] : gat_w[k * DH + (col - DH)];
    wpack[t] = f2bf(v);
}

// ---- MFMA GEMM + fused attention logits (2 row-tiles per wave) -----------
// 32 rows/wave: each B-fragment load feeds 8 MFMAs (2 independent acc
// chains) instead of 4 — halves the per-row wpack stream (64KB > 32KB L1,
// so B-loads were L1-thrash L2-latency-bound with shallow batches).
__global__ __launch_bounds__(256) void gemm_mfma(
        const float* __restrict__ x, const float* __restrict__ lin_b,
        const u16* __restrict__ wpack, const float* __restrict__ att_src,
        const float* __restrict__ att_dst, float* __restrict__ h_out,
        u16* __restrict__ xp, float* __restrict__ a_src,
        float* __restrict__ a_dst, int N) {
    int wave = threadIdx.x >> 6;
    int lane = threadIdx.x & 63;
    int row0 = blockIdx.x * 128 + wave * 32;
    if (row0 >= N) return;
    int row1 = row0 + 16;
    bool t1 = (row1 < N);
    int m = lane & 15, quad = lane >> 4;

    short8 afr0[4], afr1[4];
    {
        const float* xr0 = x + (size_t)(row0 + m) * DH + quad * 8;
        const float* xr1 = x + (size_t)((t1 ? row1 : row0) + m) * DH + quad * 8;
        #pragma unroll
        for (int ks = 0; ks < 4; ks++) {
            float4 f0 = *(const float4*)(xr0 + ks * 32);
            float4 f1 = *(const float4*)(xr0 + ks * 32 + 4);
            short8 a;
            a[0] = (short)f2bf(f0.x); a[1] = (short)f2bf(f0.y);
            a[2] = (short)f2bf(f0.z); a[3] = (short)f2bf(f0.w);
            a[4] = (short)f2bf(f1.x); a[5] = (short)f2bf(f1.y);
            a[6] = (short)f2bf(f1.z); a[7] = (short)f2bf(f1.w);
            afr0[ks] = a;
            float4 g0 = *(const float4*)(xr1 + ks * 32);
            float4 g1 = *(const float4*)(xr1 + ks * 32 + 4);
            short8 b;
            b[0] = (short)f2bf(g0.x); b[1] = (short)f2bf(g0.y);
            b[2] = (short)f2bf(g0.z); b[3] = (short)f2bf(g0.w);
            b[4] = (short)f2bf(g1.x); b[5] = (short)f2bf(g1.y);
            b[6] = (short)f2bf(g1.z); b[7] = (short)f2bf(g1.w);
            afr1[ks] = b;
        }
    }

    // ---- first half: h_in columns 0..127 ----
    #pragma unroll 4
    for (int ct = 0; ct < 8; ct++) {
        floatx4 acc0 = {0.f, 0.f, 0.f, 0.f};
        floatx4 acc1 = {0.f, 0.f, 0.f, 0.f};
        const short8* bp = (const short8*)wpack + (ct * 4) * 64 + lane;
        #pragma unroll
        for (int ks = 0; ks < 4; ks++) {
            short8 bfr = bp[ks * 64];
            acc0 = __builtin_amdgcn_mfma_f32_16x16x32_bf16(afr0[ks], bfr, acc0, 0, 0, 0);
            acc1 = __builtin_amdgcn_mfma_f32_16x16x32_bf16(afr1[ks], bfr, acc1, 0, 0, 0);
        }
        int col = ct * 16 + m;   // D: col=lane&15, row=quad*4+r
        float bias = lin_b[col];
        #pragma unroll
        for (int r = 0; r < 4; r++)
            h_out[(size_t)(row0 + quad * 4 + r) * DH + col] = acc0[r] + bias;
        if (t1) {
            #pragma unroll
            for (int r = 0; r < 4; r++)
                h_out[(size_t)(row1 + quad * 4 + r) * DH + col] = acc1[r] + bias;
        }
    }

    // ---- second half: xp columns + fused per-head logits ----
    float pS0[4], pD0[4], pS1[4], pD1[4];
    #pragma unroll
    for (int ct2 = 0; ct2 < 8; ct2++) {
        const int ct = ct2 + 8;
        const int hh = ct2 >> 1;          // head, compile-time
        floatx4 acc0 = {0.f, 0.f, 0.f, 0.f};
        floatx4 acc1 = {0.f, 0.f, 0.f, 0.f};
        const short8* bp = (const short8*)wpack + (ct * 4) * 64 + lane;
        #pragma unroll
        for (int ks = 0; ks < 4; ks++) {
            short8 bfr = bp[ks * 64];
            acc0 = __builtin_amdgcn_mfma_f32_16x16x32_bf16(afr0[ks], bfr, acc0, 0, 0, 0);
            acc1 = __builtin_amdgcn_mfma_f32_16x16x32_bf16(afr1[ks], bfr, acc1, 0, 0, 0);
        }
        int c2 = ct2 * 16 + m;            // xp column
        #pragma unroll
        for (int r = 0; r < 4; r++)
            xp[(size_t)(row0 + quad * 4 + r) * DH + c2] = f2bf(acc0[r]);
        if (t1) {
            #pragma unroll
            for (int r = 0; r < 4; r++)
                xp[(size_t)(row1 + quad * 4 + r) * DH + c2] = f2bf(acc1[r]);
        }

        // logit partials: within head hh, this ct covers channel
        // (ct2&1)*16 + m of that head
        int ch = ((ct2 & 1) << 4) + m;
        float ws = att_src[hh * CH + ch];
        float wd = att_dst[hh * CH + ch];
        if (!(ct2 & 1)) {
            #pragma unroll
            for (int r = 0; r < 4; r++) {
                pS0[r] = acc0[r] * ws; pD0[r] = acc0[r] * wd;
                pS1[r] = acc1[r] * ws; pD1[r] = acc1[r] * wd;
            }
        } else {
            #pragma unroll
            for (int r = 0; r < 4; r++) {
                pS0[r] = fmaf(acc0[r], ws, pS0[r]);
                pD0[r] = fmaf(acc0[r], wd, pD0[r]);
                pS1[r] = fmaf(acc1[r], ws, pS1[r]);
                pD1[r] = fmaf(acc1[r], wd, pD1[r]);
            }
            // reduce over the 16 m-lanes (lane bits 0..3)
            #pragma unroll
            for (int r = 0; r < 4; r++) {
                #pragma unroll
                for (int mk = 1; mk <= 8; mk <<= 1) {
                    pS0[r] += __shfl_xor(pS0[r], mk, 64);
                    pD0[r] += __shfl_xor(pD0[r], mk, 64);
                    pS1[r] += __shfl_xor(pS1[r], mk, 64);
                    pD1[r] += __shfl_xor(pD1[r], mk, 64);
                }
            }
            if (m == 0) {
                #pragma unroll
                for (int r = 0; r < 4; r++) {
                    int node = row0 + quad * 4 + r;
                    a_src[node * NH + hh] = pS0[r];
                    a_dst[node * NH + hh] = pD0[r];
                }
                if (t1) {
                    #pragma unroll
                    for (int r = 0; r < 4; r++) {
                        int node = row1 + quad * 4 + r;
                        a_src[node * NH + hh] = pS1[r];
                        a_dst[node * NH + hh] = pD1[r];
                    }
                }
            }
        }
    }
}

// ==================== CSR build v2: two-level bucket sort ====================

// ---- pass 1: bucket histogram (LDS hist, one atomic per block-bucket) ----
__global__ __launch_bounds__(256) void bucket_count(
        const int* __restrict__ ei, int E, int N, int B,
        int* __restrict__ bcount) {
    __shared__ int h[MAXB];
    for (int j = threadIdx.x; j < B; j += 256) h[j] = 0;
    __syncthreads();
    int i0 = blockIdx.x * EPB;
    int i1 = min(E, i0 + EPB);
    for (int i = i0 + threadIdx.x; i < i1; i += 256) {
        int d = min(max(ei[E + i], 0), N - 1);
        atomicAdd(&h[d >> 8], 1);
    }
    __syncthreads();
    for (int j = threadIdx.x; j < B; j += 256) {
        int c = h[j];
        if (c) atomicAdd(&bcount[j], c);
    }
}

// ---- pass 2: exclusive scan of bucket sizes; init claim cursors ----------
__global__ __launch_bounds__(512) void bucket_scan(
        const int* __restrict__ bcount, int B,
        int* __restrict__ bbase, int* __restrict__ bcur) {
    __shared__ int buf[512];
    int t = threadIdx.x;
    int v = (t < B) ? bcount[t] : 0;
    buf[t] = v;
    __syncthreads();
    for (int s = 1; s < 512; s <<= 1) {
        int add = (t >= s) ? buf[t - s] : 0;
        __syncthreads();
        buf[t] += add;
        __syncthreads();
    }
    if (t < B) { int e = buf[t] - v; bbase[t] = e; bcur[t] = e; }
}

// ---- pass 3: scatter edges into bucket segments (packed src|dlocal) ------
__global__ __launch_bounds__(256) void bucket_scatter(
        const int* __restrict__ ei, int E, int N, int B,
        int* __restrict__ bcur, unsigned* __restrict__ tmp) {
    __shared__ int h[MAXB];     // histogram, then LDS cursor
    __shared__ int base[MAXB];  // global base claimed for this block
    for (int j = threadIdx.x; j < B; j += 256) h[j] = 0;
    __syncthreads();
    int i0 = blockIdx.x * EPB;
    int i1 = min(E, i0 + EPB);
    for (int i = i0 + threadIdx.x; i < i1; i += 256) {
        int d = min(max(ei[E + i], 0), N - 1);
        atomicAdd(&h[d >> 8], 1);
    }
    __syncthreads();
    for (int j = threadIdx.x; j < B; j += 256) {
        int c = h[j];
        base[j] = c ? atomicAdd(&bcur[j], c) : 0;
    }
    __syncthreads();
    for (int j = threadIdx.x; j < B; j += 256) h[j] = 0;  // reuse as cursor
    __syncthreads();
    for (int i = i0 + threadIdx.x; i < i1; i += 256) {
        int s = min(max(ei[i], 0), N - 1);
        int d = min(max(ei[E + i], 0), N - 1);
        int b = d >> 8;
        int pos = base[b] + atomicAdd(&h[b], 1);
        tmp[pos] = (unsigned)s | ((unsigned)(d & 255) << 17);   // N<=131072
    }
}

// ---- pass 4: per-bucket LDS counting sort -> col, deg, offsets -----------
__global__ __launch_bounds__(256) void bucket_to_csr(
        const unsigned* __restrict__ tmp, const int* __restrict__ bbase,
        const int* __restrict__ bcount, int N,
        int* __restrict__ offsets, int* __restrict__ deg,
        int* __restrict__ col) {
    __shared__ int cnt[NPB];    // per-node count, then LDS cursor
    __shared__ int excl[NPB];
    int b = blockIdx.x;
    int t = threadIdx.x;        // 256 threads == NPB
    int bstart = bbase[b];
    int c = bcount[b];
    cnt[t] = 0;
    __syncthreads();
    for (int k = t; k < c; k += 256) {
        unsigned pk = tmp[bstart + k];
        atomicAdd(&cnt[pk >> 17], 1);
    }
    __syncthreads();
    int v = cnt[t];
    excl[t] = v;
    __syncthreads();
    for (int s = 1; s < 256; s <<= 1) {
        int add = (t >= s) ? excl[t - s] : 0;
        __syncthreads();
        excl[t] += add;
        __syncthreads();
    }
    int mystart = excl[t] - v;  // exclusive start within bucket
    int node = b * NPB + t;
    if (node < N) {
        offsets[node] = bstart + mystart;
        deg[node] = v;
    }
    cnt[t] = mystart;           // reuse as placement cursor
    __syncthreads();
    for (int k = t; k < c; k += 256) {
        unsigned pk = tmp[bstart + k];
        int slot = atomicAdd(&cnt[pk >> 17], 1);
        col[bstart + slot] = (int)(pk & 0x1FFFFu);
    }
}

// ---- CSR gather + fused softmax denominator (round-5 proven form) --------
// One node per wave, grid (N+3)/4 — hardware dispatcher load-balances
// (round-6 lesson: 2048-block grid-stride killed backfill, 81->175us).
__global__ __launch_bounds__(256) void csr_gather(
        const int* __restrict__ offsets, const int* __restrict__ deg,
        const int* __restrict__ col, const float* __restrict__ a_src,
        const float* __restrict__ a_dst, const u16* __restrict__ xp,
        float* __restrict__ agg, int N) {
    int node = blockIdx.x * 4 + (threadIdx.x >> 6);
    if (node >= N) return;
    int lane  = threadIdx.x & 63;
    int h     = lane >> 4;          // head for channels 2*lane, 2*lane+1
    int q     = lane & 3;           // head this lane evaluates in chunk phase
    int esl   = lane >> 2;          // edge slot this lane evaluates
    int lane2 = lane << 1;          // u16 element offset into a row

    float ad_q = a_dst[node * NH + q];

    // self-loop (s == node)
    float w = __expf(lr(a_src[node * NH + h] + a_dst[node * NH + h]));
    unsigned xv = *(const unsigned*)(xp + (size_t)node * DH + lane2);
    float acc0 = w * b2f_lo(xv);
    float acc1 = w * b2f_hi(xv);
    float denv = 0.f;               // per-lane exp sum (own edge slot, head q)

    int off = offsets[node], dg = deg[node];
    const int* cp = col + off;

#define EDGE_F(K) {                                                       \
        float e = __shfl(ev, ((K) << 2) | h, 64);                         \
        int  su = __builtin_amdgcn_readlane(s_e, (K) << 2);               \
        const u16* row = xp + ((size_t)(unsigned)su << 7);                \
        unsigned v = *(const unsigned*)(row + lane2);                     \
        acc0 = fmaf(e, b2f_lo(v), acc0);                                  \
        acc1 = fmaf(e, b2f_hi(v), acc1); }

#define EDGE_P(K) {                                                       \
        float e = ((K) < rem) ? __shfl(ev, ((K) << 2) | h, 64) : 0.f;     \
        int  su = __builtin_amdgcn_readlane(s_e, (K) << 2);               \
        const u16* row = xp + ((size_t)(unsigned)su << 7);                \
        unsigned v = *(const unsigned*)(row + lane2);                     \
        acc0 = fmaf(e, b2f_lo(v), acc0);                                  \
        acc1 = fmaf(e, b2f_hi(v), acc1); }

    for (int k0 = 0; k0 < dg; k0 += 16) {
        int rem  = dg - k0;                       // > 0
        int kidx = min(k0 + esl, dg - 1);         // clamped slot
        int s_e  = cp[kidx];
        float ev = __expf(lr(a_src[s_e * NH + q] + ad_q));
        denv += ((k0 + esl) < dg) ? ev : 0.f;
        if (rem >= 16) {
            #pragma unroll
            for (int k = 0; k < 16; k++) EDGE_F(k)
        } else {
            #pragma unroll
            for (int k = 0; k < 16; k++) EDGE_P(k)
        }
    }
#undef EDGE_F
#undef EDGE_P

    // butterfly over lanes sharing q (xor bits 2..5), then pick head h's sum
    #pragma unroll
    for (int m = 4; m <= 32; m <<= 1)
        denv += __shfl_xor(denv, m, 64);
    float den = __shfl(denv, h, 64) + w;

    float inv = 1.0f / den;
    float2 o; o.x = acc0 * inv; o.y = acc1 * inv;
    *(float2*)(agg + (size_t)node * DH + lane2) = o;   // 512B/wave coalesced
}

// ---- BN column stats: float4 rows, LDS tree reduce, direct atomicAdd -----
// SGRID 1024 (more TLP) + unroll 4 (4 loads in flight vs 1).
__global__ __launch_bounds__(256) void stats_kernel(
        const float* __restrict__ agg, int N,
        float* __restrict__ colsum, float* __restrict__ colsumsq) {
    int grp = threadIdx.x & 31;    // column quad: cols 4*grp .. 4*grp+3
    int sub = threadIdx.x >> 5;    // 0..7 row subgroup
    int c4  = grp << 2;
    floatx4 s1 = {0.f, 0.f, 0.f, 0.f}, s2 = {0.f, 0.f, 0.f, 0.f};
    int rpb = (N + gridDim.x - 1) / gridDim.x;
    int r0  = blockIdx.x * rpb;
    int r1  = min(N, r0 + rpb);
    #pragma unroll 4
    for (int r = r0 + sub; r < r1; r += 8) {
        floatx4 v = *(const floatx4*)(agg + (size_t)r * DH + c4);
        s1 += v;
        s2 += v * v;
    }
    __shared__ floatx4 red1[8][32];
    __shared__ floatx4 red2[8][32];
    red1[sub][grp] = s1;
    red2[sub][grp] = s2;
    __syncthreads();
    for (int s = 4; s >= 1; s >>= 1) {
        if (sub < s) {
            red1[sub][grp] += red1[sub + s][grp];
            red2[sub][grp] += red2[sub + s][grp];
        }
        __syncthreads();
    }
    if (sub == 0) {
        floatx4 a1 = red1[0][grp];
        floatx4 a2 = red2[0][grp];
        #pragma unroll
        for (int j = 0; j < 4; j++) {
            atomicAdd(&colsum[c4 + j],   a1[j]);
            atomicAdd(&colsumsq[c4 + j], a2[j]);
        }
    }
}

// ---- BN normalize + ELU + residual (float4, 1 pass) ----------------------
// gat_bias cancels exactly in training-mode BN (shifts column mean only)
__global__ __launch_bounds__(256) void final_kernel(
        const float* __restrict__ agg, const float* __restrict__ colsum,
        const float* __restrict__ colsumsq, const float* __restrict__ gamma,
        const float* __restrict__ beta, float* __restrict__ out, int N) {
    int t = blockIdx.x * blockDim.x + threadIdx.x;   // over N * (DH/4)
    if (t >= N * (DH / 4)) return;
    int row = t >> 5;                 // DH/4 = 32 float4 per row
    int c4  = (t & 31) << 2;
    float inv_n = 1.0f / (float)N;

    floatx4 s1 = *(const floatx4*)(colsum   + c4);
    floatx4 s2 = *(const floatx4*)(colsumsq + c4);
    floatx4 g  = *(const floatx4*)(gamma    + c4);
    floatx4 b  = *(const floatx4*)(beta     + c4);
    floatx4 a  = *(const floatx4*)(agg + (size_t)row * DH + c4);
    floatx4 o  = *(const floatx4*)(out + (size_t)row * DH + c4);

    #pragma unroll
    for (int j = 0; j < 4; j++) {
        float mu   = s1[j] * inv_n;
        float var  = s2[j] * inv_n - mu * mu;
        float rstd = rsqrtf(var + 1e-5f);
        float v = (a[j] - mu) * rstd * g[j] + b[j];
        v = v > 0.f ? v : (__expf(v) - 1.f);          // ELU(alpha=1)
        float r = o[j] + v;                            // + h_in (in d_out)
        if (!(r >= -1e30f && r <= 1e30f)) r = 512.0f;  // tripwire sentinel
        o[j] = r;
    }
    *(floatx4*)(out + (size_t)row * DH + c4) = o;
}

extern "C" void kernel_launch(void* const* d_in, const int* in_sizes, int n_in,
                              void* d_out, int out_size, void* d_ws, size_t ws_size,
                              hipStream_t stream) {
    const float* x        = (const float*)d_in[0];
    const int*   ei       = (const int*)d_in[1];
    const float* lin_w    = (const float*)d_in[2];
    const float* lin_b    = (const float*)d_in[3];
    const float* gat_w    = (const float*)d_in[4];
    const float* att_src  = (const float*)d_in[5];
    const float* att_dst  = (const float*)d_in[6];
    // d_in[7] gat_bias: cancels in training-mode BN — unused
    const float* bn_gamma = (const float*)d_in[8];
    const float* bn_beta  = (const float*)d_in[9];

    int N = in_sizes[0] / DH;
    int E = in_sizes[1] / 2;
    int B = (N + NPB - 1) / NPB;          // buckets (<=512 for N<=131072)
    int EB = (E + EPB - 1) / EPB;         // binning blocks

    // ---- ws carve (16B aligned) ----
    char* p = (char*)d_ws;
    u16*   xp      = (u16*)p;        p += (size_t)N * DH * 2;   // 25.6 MB
    float* a_src   = (float*)p;      p += (size_t)N * NH * 4;
    float* a_dst   = (float*)p;      p += (size_t)N * NH * 4;
    u16*   wpack   = (u16*)p;        p += 32768 * 2;
    int*   col     = (int*)p;        p += (size_t)E * 4;        //  6.4 MB
    int*   offsets = (int*)p;        p += (size_t)N * 4;
    int*   deg     = (int*)p;        p += (size_t)N * 4;
    int*   bbase   = (int*)p;        p += MAXB * 4;
    int*   bcur    = (int*)p;        p += MAXB * 4;
    char* zero_begin = p;
    int*   bcount  = (int*)p;        p += MAXB * 4;
    float* colsum  = (float*)p;      p += DH * 4;
    float* colsumsq= (float*)p;      p += DH * 4;
    size_t zero_bytes = (size_t)(p - zero_begin);
    float* agg     = (float*)p;      // N*DH fp32 (51.2 MB; fits — proven)
    unsigned* tmp  = (unsigned*)agg; // aliased: tmp dead before agg written

    hipMemsetAsync(zero_begin, 0, zero_bytes, stream);

    repack_w<<<(16 * 4 * 64 * 8) / 256, 256, 0, stream>>>(lin_w, gat_w, wpack);

    gemm_mfma<<<(N + 127) / 128, 256, 0, stream>>>(x, lin_b, wpack, att_src,
                                                   att_dst, (float*)d_out, xp,
                                                   a_src, a_dst, N);

    // CSR build v2 (bucketed, LDS-staged)
    bucket_count<<<EB, 256, 0, stream>>>(ei, E, N, B, bcount);
    bucket_scan<<<1, 512, 0, stream>>>(bcount, B, bbase, bcur);
    bucket_scatter<<<EB, 256, 0, stream>>>(ei, E, N, B, bcur, tmp);
    bucket_to_csr<<<B, 256, 0, stream>>>(tmp, bbase, bcount, N,
                                         offsets, deg, col);

    csr_gather<<<(N + 3) / 4, 256, 0, stream>>>(offsets, deg, col, a_src,
                                                a_dst, xp, agg, N);
    stats_kernel<<<SGRID, 256, 0, stream>>>(agg, N, colsum, colsumsq);
    final_kernel<<<(N * (DH / 4) + 255) / 256, 256, 0, stream>>>(
        agg, colsum, colsumsq, bn_gamma, bn_beta, (float*)d_out, N);
}

// Round 9
// 325.241 us; speedup vs baseline: 1.2766x; 1.2766x over previous
//
#include <hip/hip_runtime.h>
#include <stdint.h>

typedef unsigned short u16;
typedef __attribute__((ext_vector_type(8))) short short8;
typedef __attribute__((ext_vector_type(4))) float floatx4;

#define DH 128   // D = H*C
#define NH 4     // heads
#define CH 32    // channels per head

#define NPB  256   // nodes per bucket (dst >> 8) — dlocal fits 8 bits
#define MAXB 512   // max buckets (N <= 131072)
#define EPB 8192   // edges per block in binning passes
#define SGRID 512  // stats pass-1 blocks (pass2 assumes exactly 512)

__device__ __forceinline__ float bf2f(u16 u) {
    union { unsigned int i; float f; } c; c.i = ((unsigned int)u) << 16; return c.f;
}
__device__ __forceinline__ u16 f2bf(float f) {
    union { float f; unsigned int i; } c; c.f = f;
    unsigned int x = c.i;
    x += 0x7FFFu + ((x >> 16) & 1u);   // round-to-nearest-even
    return (u16)(x >> 16);
}
// unpack a u32 holding two bf16 (lo = even channel, hi = odd channel)
__device__ __forceinline__ float b2f_lo(unsigned v) {
    union { unsigned u; float f; } c; c.u = v << 16; return c.f;
}
__device__ __forceinline__ float b2f_hi(unsigned v) {
    union { unsigned u; float f; } c; c.u = v & 0xffff0000u; return c.f;
}
// leaky_relu(x,0.2) branchless
__device__ __forceinline__ float lr(float x) { return fmaxf(x, 0.2f * x); }

// ---- repack [lin_w | gat_w] (f32) into MFMA B-fragment order (bf16) ------
__global__ void repack_w(const float* __restrict__ lin_w, const float* __restrict__ gat_w,
                         u16* __restrict__ wpack) {
    int t = blockIdx.x * blockDim.x + threadIdx.x;   // 0 .. 32767
    int j    = t & 7;
    int lane = (t >> 3) & 63;
    int ks   = (t >> 9) & 3;
    int ct   = t >> 11;
    int k    = ks * 32 + (lane >> 4) * 8 + j;
    int col  = ct * 16 + (lane & 15);
    float v = (col < DH) ? lin_w[k * DH + col] : gat_w[k * DH + (col - DH)];
    wpack[t] = f2bf(v);
}

// ---- MFMA GEMM + fused attention logits (round-7 proven form) ------------
__global__ __launch_bounds__(256) void gemm_mfma(
        const float* __restrict__ x, const float* __restrict__ lin_b,
        const u16* __restrict__ wpack, const float* __restrict__ att_src,
        const float* __restrict__ att_dst, float* __restrict__ h_out,
        u16* __restrict__ xp, float* __restrict__ a_src,
        float* __restrict__ a_dst, int N) {
    int wave = threadIdx.x >> 6;
    int lane = threadIdx.x & 63;
    int rowBase = blockIdx.x * 64 + wave * 16;
    if (rowBase >= N) return;
    int m = lane & 15, quad = lane >> 4;

    short8 afr[4];
    const float* xrow = x + (size_t)(rowBase + m) * DH + quad * 8;
    #pragma unroll
    for (int ks = 0; ks < 4; ks++) {
        float4 f0 = *(const float4*)(xrow + ks * 32);
        float4 f1 = *(const float4*)(xrow + ks * 32 + 4);
        short8 a;
        a[0] = (short)f2bf(f0.x); a[1] = (short)f2bf(f0.y);
        a[2] = (short)f2bf(f0.z); a[3] = (short)f2bf(f0.w);
        a[4] = (short)f2bf(f1.x); a[5] = (short)f2bf(f1.y);
        a[6] = (short)f2bf(f1.z); a[7] = (short)f2bf(f1.w);
        afr[ks] = a;
    }

    // ---- first half: h_in columns 0..127 ----
    #pragma unroll 4
    for (int ct = 0; ct < 8; ct++) {
        floatx4 acc = {0.f, 0.f, 0.f, 0.f};
        const short8* bp = (const short8*)wpack + (ct * 4) * 64 + lane;
        #pragma unroll
        for (int ks = 0; ks < 4; ks++) {
            short8 bfr = bp[ks * 64];
            acc = __builtin_amdgcn_mfma_f32_16x16x32_bf16(afr[ks], bfr, acc, 0, 0, 0);
        }
        int col = ct * 16 + m;   // D: col=lane&15, row=quad*4+r
        float bias = lin_b[col];
        #pragma unroll
        for (int r = 0; r < 4; r++)
            h_out[(size_t)(rowBase + quad * 4 + r) * DH + col] = acc[r] + bias;
    }

    // ---- second half: xp columns + fused per-head logits ----
    float pS[4], pD[4];
    #pragma unroll
    for (int ct2 = 0; ct2 < 8; ct2++) {
        const int ct = ct2 + 8;
        const int hh = ct2 >> 1;          // head, compile-time
        floatx4 acc = {0.f, 0.f, 0.f, 0.f};
        const short8* bp = (const short8*)wpack + (ct * 4) * 64 + lane;
        #pragma unroll
        for (int ks = 0; ks < 4; ks++) {
            short8 bfr = bp[ks * 64];
            acc = __builtin_amdgcn_mfma_f32_16x16x32_bf16(afr[ks], bfr, acc, 0, 0, 0);
        }
        int c2 = ct2 * 16 + m;            // xp column
        #pragma unroll
        for (int r = 0; r < 4; r++)
            xp[(size_t)(rowBase + quad * 4 + r) * DH + c2] = f2bf(acc[r]);

        // logit partials: within head hh, this ct covers channel
        // (ct2&1)*16 + m of that head
        int ch = ((ct2 & 1) << 4) + m;
        float ws = att_src[hh * CH + ch];
        float wd = att_dst[hh * CH + ch];
        if (!(ct2 & 1)) {
            #pragma unroll
            for (int r = 0; r < 4; r++) { pS[r] = acc[r] * ws; pD[r] = acc[r] * wd; }
        } else {
            #pragma unroll
            for (int r = 0; r < 4; r++) {
                pS[r] = fmaf(acc[r], ws, pS[r]);
                pD[r] = fmaf(acc[r], wd, pD[r]);
            }
            // reduce over the 16 m-lanes (lane bits 0..3)
            #pragma unroll
            for (int r = 0; r < 4; r++) {
                #pragma unroll
                for (int mk = 1; mk <= 8; mk <<= 1) {
                    pS[r] += __shfl_xor(pS[r], mk, 64);
                    pD[r] += __shfl_xor(pD[r], mk, 64);
                }
            }
            if (m == 0) {
                #pragma unroll
                for (int r = 0; r < 4; r++) {
                    int node = rowBase + quad * 4 + r;
                    a_src[node * NH + hh] = pS[r];
                    a_dst[node * NH + hh] = pD[r];
                }
            }
        }
    }
}

// ==================== CSR build v2: two-level bucket sort ====================

// ---- pass 1: bucket histogram (LDS hist, one atomic per block-bucket) ----
__global__ __launch_bounds__(256) void bucket_count(
        const int* __restrict__ ei, int E, int N, int B,
        int* __restrict__ bcount) {
    __shared__ int h[MAXB];
    for (int j = threadIdx.x; j < B; j += 256) h[j] = 0;
    __syncthreads();
    int i0 = blockIdx.x * EPB;
    int i1 = min(E, i0 + EPB);
    for (int i = i0 + threadIdx.x; i < i1; i += 256) {
        int d = min(max(ei[E + i], 0), N - 1);
        atomicAdd(&h[d >> 8], 1);
    }
    __syncthreads();
    for (int j = threadIdx.x; j < B; j += 256) {
        int c = h[j];
        if (c) atomicAdd(&bcount[j], c);
    }
}

// ---- pass 2: exclusive scan of bucket sizes; init claim cursors ----------
__global__ __launch_bounds__(512) void bucket_scan(
        const int* __restrict__ bcount, int B,
        int* __restrict__ bbase, int* __restrict__ bcur) {
    __shared__ int buf[512];
    int t = threadIdx.x;
    int v = (t < B) ? bcount[t] : 0;
    buf[t] = v;
    __syncthreads();
    for (int s = 1; s < 512; s <<= 1) {
        int add = (t >= s) ? buf[t - s] : 0;
        __syncthreads();
        buf[t] += add;
        __syncthreads();
    }
    if (t < B) { int e = buf[t] - v; bbase[t] = e; bcur[t] = e; }
}

// ---- pass 3: scatter edges into bucket segments (packed src|dlocal) ------
__global__ __launch_bounds__(256) void bucket_scatter(
        const int* __restrict__ ei, int E, int N, int B,
        int* __restrict__ bcur, unsigned* __restrict__ tmp) {
    __shared__ int h[MAXB];     // histogram, then LDS cursor
    __shared__ int base[MAXB];  // global base claimed for this block
    for (int j = threadIdx.x; j < B; j += 256) h[j] = 0;
    __syncthreads();
    int i0 = blockIdx.x * EPB;
    int i1 = min(E, i0 + EPB);
    for (int i = i0 + threadIdx.x; i < i1; i += 256) {
        int d = min(max(ei[E + i], 0), N - 1);
        atomicAdd(&h[d >> 8], 1);
    }
    __syncthreads();
    for (int j = threadIdx.x; j < B; j += 256) {
        int c = h[j];
        base[j] = c ? atomicAdd(&bcur[j], c) : 0;
    }
    __syncthreads();
    for (int j = threadIdx.x; j < B; j += 256) h[j] = 0;  // reuse as cursor
    __syncthreads();
    for (int i = i0 + threadIdx.x; i < i1; i += 256) {
        int s = min(max(ei[i], 0), N - 1);
        int d = min(max(ei[E + i], 0), N - 1);
        int b = d >> 8;
        int pos = base[b] + atomicAdd(&h[b], 1);
        tmp[pos] = (unsigned)s | ((unsigned)(d & 255) << 17);   // N<=131072
    }
}

// ---- pass 4: per-bucket LDS counting sort -> col, deg, offsets -----------
__global__ __launch_bounds__(256) void bucket_to_csr(
        const unsigned* __restrict__ tmp, const int* __restrict__ bbase,
        const int* __restrict__ bcount, int N,
        int* __restrict__ offsets, int* __restrict__ deg,
        int* __restrict__ col) {
    __shared__ int cnt[NPB];    // per-node count, then LDS cursor
    __shared__ int excl[NPB];
    int b = blockIdx.x;
    int t = threadIdx.x;        // 256 threads == NPB
    int bstart = bbase[b];
    int c = bcount[b];
    cnt[t] = 0;
    __syncthreads();
    for (int k = t; k < c; k += 256) {
        unsigned pk = tmp[bstart + k];
        atomicAdd(&cnt[pk >> 17], 1);
    }
    __syncthreads();
    int v = cnt[t];
    excl[t] = v;
    __syncthreads();
    for (int s = 1; s < 256; s <<= 1) {
        int add = (t >= s) ? excl[t - s] : 0;
        __syncthreads();
        excl[t] += add;
        __syncthreads();
    }
    int mystart = excl[t] - v;  // exclusive start within bucket
    int node = b * NPB + t;
    if (node < N) {
        offsets[node] = bstart + mystart;
        deg[node] = v;
    }
    cnt[t] = mystart;           // reuse as placement cursor
    __syncthreads();
    for (int k = t; k < c; k += 256) {
        unsigned pk = tmp[bstart + k];
        int slot = atomicAdd(&cnt[pk >> 17], 1);
        col[bstart + slot] = (int)(pk & 0x1FFFFu);
    }
}

// ---- CSR gather + fused softmax denominator (round-5 proven form) --------
// One node per wave, grid (N+3)/4 — hardware dispatcher load-balances
// (round-6 lesson: 2048-block grid-stride killed backfill, 81->175us).
__global__ __launch_bounds__(256) void csr_gather(
        const int* __restrict__ offsets, const int* __restrict__ deg,
        const int* __restrict__ col, const float* __restrict__ a_src,
        const float* __restrict__ a_dst, const u16* __restrict__ xp,
        float* __restrict__ agg, int N) {
    int node = blockIdx.x * 4 + (threadIdx.x >> 6);
    if (node >= N) return;
    int lane  = threadIdx.x & 63;
    int h     = lane >> 4;          // head for channels 2*lane, 2*lane+1
    int q     = lane & 3;           // head this lane evaluates in chunk phase
    int esl   = lane >> 2;          // edge slot this lane evaluates
    int lane2 = lane << 1;          // u16 element offset into a row

    float ad_q = a_dst[node * NH + q];

    // self-loop (s == node)
    float w = __expf(lr(a_src[node * NH + h] + a_dst[node * NH + h]));
    unsigned xv = *(const unsigned*)(xp + (size_t)node * DH + lane2);
    float acc0 = w * b2f_lo(xv);
    float acc1 = w * b2f_hi(xv);
    float denv = 0.f;               // per-lane exp sum (own edge slot, head q)

    int off = offsets[node], dg = deg[node];
    const int* cp = col + off;

#define EDGE_F(K) {                                                       \
        float e = __shfl(ev, ((K) << 2) | h, 64);                         \
        int  su = __builtin_amdgcn_readlane(s_e, (K) << 2);               \
        const u16* row = xp + ((size_t)(unsigned)su << 7);                \
        unsigned v = *(const unsigned*)(row + lane2);                     \
        acc0 = fmaf(e, b2f_lo(v), acc0);                                  \
        acc1 = fmaf(e, b2f_hi(v), acc1); }

#define EDGE_P(K) {                                                       \
        float e = ((K) < rem) ? __shfl(ev, ((K) << 2) | h, 64) : 0.f;     \
        int  su = __builtin_amdgcn_readlane(s_e, (K) << 2);               \
        const u16* row = xp + ((size_t)(unsigned)su << 7);                \
        unsigned v = *(const unsigned*)(row + lane2);                     \
        acc0 = fmaf(e, b2f_lo(v), acc0);                                  \
        acc1 = fmaf(e, b2f_hi(v), acc1); }

    for (int k0 = 0; k0 < dg; k0 += 16) {
        int rem  = dg - k0;                       // > 0
        int kidx = min(k0 + esl, dg - 1);         // clamped slot
        int s_e  = cp[kidx];
        float ev = __expf(lr(a_src[s_e * NH + q] + ad_q));
        denv += ((k0 + esl) < dg) ? ev : 0.f;
        if (rem >= 16) {
            #pragma unroll
            for (int k = 0; k < 16; k++) EDGE_F(k)
        } else {
            #pragma unroll
            for (int k = 0; k < 16; k++) EDGE_P(k)
        }
    }
#undef EDGE_F
#undef EDGE_P

    // butterfly over lanes sharing q (xor bits 2..5), then pick head h's sum
    #pragma unroll
    for (int m = 4; m <= 32; m <<= 1)
        denv += __shfl_xor(denv, m, 64);
    float den = __shfl(denv, h, 64) + w;

    float inv = 1.0f / den;
    float2 o; o.x = acc0 * inv; o.y = acc1 * inv;
    *(float2*)(agg + (size_t)node * DH + lane2) = o;   // 512B/wave coalesced
}

// ---- BN stats pass 1: float4 rows, LDS tree, write partials (NO atomics)
// Round-8 diagnosis: same-address fp32 atomicAdd ~100ns serialized; 262K
// atomics over 256 addresses = ~106us (matched round-2 exactly). Partials
// to global instead (round-3 pass1, which was proven fast).
__global__ __launch_bounds__(256) void stats_pass1(
        const float* __restrict__ agg, int N, float* __restrict__ partial) {
    int grp = threadIdx.x & 31;    // column quad: cols 4*grp .. 4*grp+3
    int sub = threadIdx.x >> 5;    // 0..7 row subgroup
    int c4  = grp << 2;
    floatx4 s1 = {0.f, 0.f, 0.f, 0.f}, s2 = {0.f, 0.f, 0.f, 0.f};
    int rpb = (N + gridDim.x - 1) / gridDim.x;
    int r0  = blockIdx.x * rpb;
    int r1  = min(N, r0 + rpb);
    for (int r = r0 + sub; r < r1; r += 8) {
        floatx4 v = *(const floatx4*)(agg + (size_t)r * DH + c4);
        s1 += v;
        s2 += v * v;
    }
    __shared__ floatx4 red1[8][32];
    __shared__ floatx4 red2[8][32];
    red1[sub][grp] = s1;
    red2[sub][grp] = s2;
    __syncthreads();
    for (int s = 4; s >= 1; s >>= 1) {
        if (sub < s) {
            red1[sub][grp] += red1[sub + s][grp];
            red2[sub][grp] += red2[sub + s][grp];
        }
        __syncthreads();
    }
    if (sub == 0) {
        float* pb = partial + (size_t)blockIdx.x * 256;
        *(floatx4*)(pb + c4)       = red1[0][grp];
        *(floatx4*)(pb + 128 + c4) = red2[0][grp];
    }
}

// ---- BN stats pass 2: reduce [512][256] partials, no atomics -------------
// 2 blocks x 1024 threads (block 0 -> colsum, block 1 -> colsumsq). Each
// thread: 64 coalesced loads, unroll 8 (8 in flight — round-3's 1-block
// pass2 failed at 1 load in flight x 512 serial iters = 120us).
__global__ __launch_bounds__(1024) void stats_pass2(
        const float* __restrict__ partial,
        float* __restrict__ colsum, float* __restrict__ colsumsq) {
    int which = blockIdx.x;           // 0: sum, 1: sumsq
    int c   = threadIdx.x & 127;      // column
    int seg = threadIdx.x >> 7;       // 0..7, 64 partial-rows each
    const float* base = partial + which * 128 + c;
    float acc = 0.f;
    int b0 = seg * 64;
    #pragma unroll 8
    for (int b = b0; b < b0 + 64; b++)
        acc += base[(size_t)b * 256];
    __shared__ float red[8][128];
    red[seg][c] = acc;
    __syncthreads();
    if (seg == 0) {
        float s = red[0][c] + red[1][c] + red[2][c] + red[3][c]
                + red[4][c] + red[5][c] + red[6][c] + red[7][c];
        if (which == 0) colsum[c] = s; else colsumsq[c] = s;
    }
}

// ---- BN normalize + ELU + residual (float4, 1 pass) ----------------------
// gat_bias cancels exactly in training-mode BN (shifts column mean only)
__global__ __launch_bounds__(256) void final_kernel(
        const float* __restrict__ agg, const float* __restrict__ colsum,
        const float* __restrict__ colsumsq, const float* __restrict__ gamma,
        const float* __restrict__ beta, float* __restrict__ out, int N) {
    int t = blockIdx.x * blockDim.x + threadIdx.x;   // over N * (DH/4)
    if (t >= N * (DH / 4)) return;
    int row = t >> 5;                 // DH/4 = 32 float4 per row
    int c4  = (t & 31) << 2;
    float inv_n = 1.0f / (float)N;

    floatx4 s1 = *(const floatx4*)(colsum   + c4);
    floatx4 s2 = *(const floatx4*)(colsumsq + c4);
    floatx4 g  = *(const floatx4*)(gamma    + c4);
    floatx4 b  = *(const floatx4*)(beta     + c4);
    floatx4 a  = *(const floatx4*)(agg + (size_t)row * DH + c4);
    floatx4 o  = *(const floatx4*)(out + (size_t)row * DH + c4);

    #pragma unroll
    for (int j = 0; j < 4; j++) {
        float mu   = s1[j] * inv_n;
        float var  = s2[j] * inv_n - mu * mu;
        float rstd = rsqrtf(var + 1e-5f);
        float v = (a[j] - mu) * rstd * g[j] + b[j];
        v = v > 0.f ? v : (__expf(v) - 1.f);          // ELU(alpha=1)
        float r = o[j] + v;                            // + h_in (in d_out)
        if (!(r >= -1e30f && r <= 1e30f)) r = 512.0f;  // tripwire sentinel
        o[j] = r;
    }
    *(floatx4*)(out + (size_t)row * DH + c4) = o;
}

extern "C" void kernel_launch(void* const* d_in, const int* in_sizes, int n_in,
                              void* d_out, int out_size, void* d_ws, size_t ws_size,
                              hipStream_t stream) {
    const float* x        = (const float*)d_in[0];
    const int*   ei       = (const int*)d_in[1];
    const float* lin_w    = (const float*)d_in[2];
    const float* lin_b    = (const float*)d_in[3];
    const float* gat_w    = (const float*)d_in[4];
    const float* att_src  = (const float*)d_in[5];
    const float* att_dst  = (const float*)d_in[6];
    // d_in[7] gat_bias: cancels in training-mode BN — unused
    const float* bn_gamma = (const float*)d_in[8];
    const float* bn_beta  = (const float*)d_in[9];

    int N = in_sizes[0] / DH;
    int E = in_sizes[1] / 2;
    int B = (N + NPB - 1) / NPB;          // buckets (<=512 for N<=131072)
    int EB = (E + EPB - 1) / EPB;         // binning blocks

    // ---- ws carve (16B aligned) ----
    char* p = (char*)d_ws;
    u16*   xp      = (u16*)p;        p += (size_t)N * DH * 2;   // 25.6 MB
    float* a_src   = (float*)p;      p += (size_t)N * NH * 4;
    float* a_dst   = (float*)p;      p += (size_t)N * NH * 4;
    u16*   wpack   = (u16*)p;        p += 32768 * 2;
    int*   col     = (int*)p;        p += (size_t)E * 4;        //  6.4 MB
    int*   offsets = (int*)p;        p += (size_t)N * 4;
    int*   deg     = (int*)p;        p += (size_t)N * 4;
    int*   bbase   = (int*)p;        p += MAXB * 4;
    int*   bcur    = (int*)p;        p += MAXB * 4;
    float* partial = (float*)p;      p += (size_t)SGRID * 256 * 4;  // 512 KB
    char* zero_begin = p;
    int*   bcount  = (int*)p;        p += MAXB * 4;
    float* colsum  = (float*)p;      p += DH * 4;
    float* colsumsq= (float*)p;      p += DH * 4;
    size_t zero_bytes = (size_t)(p - zero_begin);
    float* agg     = (float*)p;      // N*DH fp32 (51.2 MB; fits — proven)
    unsigned* tmp  = (unsigned*)agg; // aliased: tmp dead before agg written

    hipMemsetAsync(zero_begin, 0, zero_bytes, stream);

    repack_w<<<(16 * 4 * 64 * 8) / 256, 256, 0, stream>>>(lin_w, gat_w, wpack);

    gemm_mfma<<<(N + 63) / 64, 256, 0, stream>>>(x, lin_b, wpack, att_src,
                                                 att_dst, (float*)d_out, xp,
                                                 a_src, a_dst, N);

    // CSR build v2 (bucketed, LDS-staged)
    bucket_count<<<EB, 256, 0, stream>>>(ei, E, N, B, bcount);
    bucket_scan<<<1, 512, 0, stream>>>(bcount, B, bbase, bcur);
    bucket_scatter<<<EB, 256, 0, stream>>>(ei, E, N, B, bcur, tmp);
    bucket_to_csr<<<B, 256, 0, stream>>>(tmp, bbase, bcount, N,
                                         offsets, deg, col);

    csr_gather<<<(N + 3) / 4, 256, 0, stream>>>(offsets, deg, col, a_src,
                                                a_dst, xp, agg, N);
    stats_pass1<<<SGRID, 256, 0, stream>>>(agg, N, partial);
    stats_pass2<<<2, 1024, 0, stream>>>(partial, colsum, colsumsq);
    final_kernel<<<(N * (DH / 4) + 255) / 256, 256, 0, stream>>>(
        agg, colsum, colsumsq, bn_gamma, bn_beta, (float*)d_out, N);
}

// Round 10
// 319.708 us; speedup vs baseline: 1.2987x; 1.0173x over previous
//
#include <hip/hip_runtime.h>
#include <stdint.h>

typedef unsigned short u16;
typedef __attribute__((ext_vector_type(8))) short short8;
typedef __attribute__((ext_vector_type(4))) float floatx4;

#define DH 128   // D = H*C
#define NH 4     // heads
#define CH 32    // channels per head

#define NPB  256   // nodes per bucket (dst >> 8) — dlocal fits 8 bits
#define MAXB 512   // max buckets (N <= 131072)
#define EPB 8192   // edges per block in binning passes
#define SGRID 512  // stats pass-1 blocks (pass2 assumes exactly 512)

__device__ __forceinline__ float bf2f(u16 u) {
    union { unsigned int i; float f; } c; c.i = ((unsigned int)u) << 16; return c.f;
}
__device__ __forceinline__ u16 f2bf(float f) {
    union { float f; unsigned int i; } c; c.f = f;
    unsigned int x = c.i;
    x += 0x7FFFu + ((x >> 16) & 1u);   // round-to-nearest-even
    return (u16)(x >> 16);
}
// unpack a u32 holding two bf16 (lo = even channel, hi = odd channel)
__device__ __forceinline__ float b2f_lo(unsigned v) {
    union { unsigned u; float f; } c; c.u = v << 16; return c.f;
}
__device__ __forceinline__ float b2f_hi(unsigned v) {
    union { unsigned u; float f; } c; c.u = v & 0xffff0000u; return c.f;
}
// leaky_relu(x,0.2) branchless
__device__ __forceinline__ float lr(float x) { return fmaxf(x, 0.2f * x); }

// ---- repack [lin_w | gat_w] (f32) into MFMA B-fragment order (bf16) ------
__global__ void repack_w(const float* __restrict__ lin_w, const float* __restrict__ gat_w,
                         u16* __restrict__ wpack) {
    int t = blockIdx.x * blockDim.x + threadIdx.x;   // 0 .. 32767
    int j    = t & 7;
    int lane = (t >> 3) & 63;
    int ks   = (t >> 9) & 3;
    int ct   = t >> 11;
    int k    = ks * 32 + (lane >> 4) * 8 + j;
    int col  = ct * 16 + (lane & 15);
    float v = (col < DH) ? lin_w[k * DH + col] : gat_w[k * DH + (col - DH)];
    wpack[t] = f2bf(v);
}

// ---- MFMA GEMM + fused attention logits, LDS-staged B --------------------
// Round-10 change: each wave previously streamed all 64KB of wpack through
// a 32KB L1 (thrash; 4 loads in flight between MFMA batches -> L2-latency-
// bound). Now the block stages wpack into LDS once (coalesced float4),
// B-fragments come from ds_read_b128. 512 thr/block (8 waves, 128 rows);
// 64KB LDS -> 2 blocks/CU -> 4 waves/SIMD.
__global__ __launch_bounds__(512) void gemm_mfma(
        const float* __restrict__ x, const float* __restrict__ lin_b,
        const u16* __restrict__ wpack, const float* __restrict__ att_src,
        const float* __restrict__ att_dst, float* __restrict__ h_out,
        u16* __restrict__ xp, float* __restrict__ a_src,
        float* __restrict__ a_dst, int N) {
    __shared__ u16 wlds[32768];   // 64 KB
    {
        float4* dstv = (float4*)wlds;
        const float4* srcv = (const float4*)wpack;
        #pragma unroll
        for (int i = 0; i < 8; i++)
            dstv[threadIdx.x + i * 512] = srcv[threadIdx.x + i * 512];
    }
    __syncthreads();

    int wave = threadIdx.x >> 6;
    int lane = threadIdx.x & 63;
    int rowBase = blockIdx.x * 128 + wave * 16;
    if (rowBase >= N) return;
    int m = lane & 15, quad = lane >> 4;

    short8 afr[4];
    const float* xrow = x + (size_t)(rowBase + m) * DH + quad * 8;
    #pragma unroll
    for (int ks = 0; ks < 4; ks++) {
        float4 f0 = *(const float4*)(xrow + ks * 32);
        float4 f1 = *(const float4*)(xrow + ks * 32 + 4);
        short8 a;
        a[0] = (short)f2bf(f0.x); a[1] = (short)f2bf(f0.y);
        a[2] = (short)f2bf(f0.z); a[3] = (short)f2bf(f0.w);
        a[4] = (short)f2bf(f1.x); a[5] = (short)f2bf(f1.y);
        a[6] = (short)f2bf(f1.z); a[7] = (short)f2bf(f1.w);
        afr[ks] = a;
    }

    // ---- first half: h_in columns 0..127 ----
    #pragma unroll 4
    for (int ct = 0; ct < 8; ct++) {
        floatx4 acc = {0.f, 0.f, 0.f, 0.f};
        const short8* bp = (const short8*)wlds + (ct * 4) * 64 + lane;
        #pragma unroll
        for (int ks = 0; ks < 4; ks++) {
            short8 bfr = bp[ks * 64];
            acc = __builtin_amdgcn_mfma_f32_16x16x32_bf16(afr[ks], bfr, acc, 0, 0, 0);
        }
        int col = ct * 16 + m;   // D: col=lane&15, row=quad*4+r
        float bias = lin_b[col];
        #pragma unroll
        for (int r = 0; r < 4; r++)
            h_out[(size_t)(rowBase + quad * 4 + r) * DH + col] = acc[r] + bias;
    }

    // ---- second half: xp columns + fused per-head logits ----
    float pS[4], pD[4];
    #pragma unroll
    for (int ct2 = 0; ct2 < 8; ct2++) {
        const int ct = ct2 + 8;
        const int hh = ct2 >> 1;          // head, compile-time
        floatx4 acc = {0.f, 0.f, 0.f, 0.f};
        const short8* bp = (const short8*)wlds + (ct * 4) * 64 + lane;
        #pragma unroll
        for (int ks = 0; ks < 4; ks++) {
            short8 bfr = bp[ks * 64];
            acc = __builtin_amdgcn_mfma_f32_16x16x32_bf16(afr[ks], bfr, acc, 0, 0, 0);
        }
        int c2 = ct2 * 16 + m;            // xp column
        #pragma unroll
        for (int r = 0; r < 4; r++)
            xp[(size_t)(rowBase + quad * 4 + r) * DH + c2] = f2bf(acc[r]);

        // logit partials: within head hh, this ct covers channel
        // (ct2&1)*16 + m of that head
        int ch = ((ct2 & 1) << 4) + m;
        float ws = att_src[hh * CH + ch];
        float wd = att_dst[hh * CH + ch];
        if (!(ct2 & 1)) {
            #pragma unroll
            for (int r = 0; r < 4; r++) { pS[r] = acc[r] * ws; pD[r] = acc[r] * wd; }
        } else {
            #pragma unroll
            for (int r = 0; r < 4; r++) {
                pS[r] = fmaf(acc[r], ws, pS[r]);
                pD[r] = fmaf(acc[r], wd, pD[r]);
            }
            // reduce over the 16 m-lanes (lane bits 0..3)
            #pragma unroll
            for (int r = 0; r < 4; r++) {
                #pragma unroll
                for (int mk = 1; mk <= 8; mk <<= 1) {
                    pS[r] += __shfl_xor(pS[r], mk, 64);
                    pD[r] += __shfl_xor(pD[r], mk, 64);
                }
            }
            if (m == 0) {
                #pragma unroll
                for (int r = 0; r < 4; r++) {
                    int node = rowBase + quad * 4 + r;
                    a_src[node * NH + hh] = pS[r];
                    a_dst[node * NH + hh] = pD[r];
                }
            }
        }
    }
}

// ==================== CSR build v2: two-level bucket sort ====================

// ---- pass 1: bucket histogram (LDS hist, one atomic per block-bucket) ----
__global__ __launch_bounds__(256) void bucket_count(
        const int* __restrict__ ei, int E, int N, int B,
        int* __restrict__ bcount) {
    __shared__ int h[MAXB];
    for (int j = threadIdx.x; j < B; j += 256) h[j] = 0;
    __syncthreads();
    int i0 = blockIdx.x * EPB;
    int i1 = min(E, i0 + EPB);
    for (int i = i0 + threadIdx.x; i < i1; i += 256) {
        int d = min(max(ei[E + i], 0), N - 1);
        atomicAdd(&h[d >> 8], 1);
    }
    __syncthreads();
    for (int j = threadIdx.x; j < B; j += 256) {
        int c = h[j];
        if (c) atomicAdd(&bcount[j], c);
    }
}

// ---- pass 2: exclusive scan of bucket sizes; init claim cursors ----------
__global__ __launch_bounds__(512) void bucket_scan(
        const int* __restrict__ bcount, int B,
        int* __restrict__ bbase, int* __restrict__ bcur) {
    __shared__ int buf[512];
    int t = threadIdx.x;
    int v = (t < B) ? bcount[t] : 0;
    buf[t] = v;
    __syncthreads();
    for (int s = 1; s < 512; s <<= 1) {
        int add = (t >= s) ? buf[t - s] : 0;
        __syncthreads();
        buf[t] += add;
        __syncthreads();
    }
    if (t < B) { int e = buf[t] - v; bbase[t] = e; bcur[t] = e; }
}

// ---- pass 3: scatter edges into bucket segments (packed src|dlocal) ------
__global__ __launch_bounds__(256) void bucket_scatter(
        const int* __restrict__ ei, int E, int N, int B,
        int* __restrict__ bcur, unsigned* __restrict__ tmp) {
    __shared__ int h[MAXB];     // histogram, then LDS cursor
    __shared__ int base[MAXB];  // global base claimed for this block
    for (int j = threadIdx.x; j < B; j += 256) h[j] = 0;
    __syncthreads();
    int i0 = blockIdx.x * EPB;
    int i1 = min(E, i0 + EPB);
    for (int i = i0 + threadIdx.x; i < i1; i += 256) {
        int d = min(max(ei[E + i], 0), N - 1);
        atomicAdd(&h[d >> 8], 1);
    }
    __syncthreads();
    for (int j = threadIdx.x; j < B; j += 256) {
        int c = h[j];
        base[j] = c ? atomicAdd(&bcur[j], c) : 0;
    }
    __syncthreads();
    for (int j = threadIdx.x; j < B; j += 256) h[j] = 0;  // reuse as cursor
    __syncthreads();
    for (int i = i0 + threadIdx.x; i < i1; i += 256) {
        int s = min(max(ei[i], 0), N - 1);
        int d = min(max(ei[E + i], 0), N - 1);
        int b = d >> 8;
        int pos = base[b] + atomicAdd(&h[b], 1);
        tmp[pos] = (unsigned)s | ((unsigned)(d & 255) << 17);   // N<=131072
    }
}

// ---- pass 4: per-bucket LDS counting sort -> col, deg, offsets -----------
__global__ __launch_bounds__(256) void bucket_to_csr(
        const unsigned* __restrict__ tmp, const int* __restrict__ bbase,
        const int* __restrict__ bcount, int N,
        int* __restrict__ offsets, int* __restrict__ deg,
        int* __restrict__ col) {
    __shared__ int cnt[NPB];    // per-node count, then LDS cursor
    __shared__ int excl[NPB];
    int b = blockIdx.x;
    int t = threadIdx.x;        // 256 threads == NPB
    int bstart = bbase[b];
    int c = bcount[b];
    cnt[t] = 0;
    __syncthreads();
    for (int k = t; k < c; k += 256) {
        unsigned pk = tmp[bstart + k];
        atomicAdd(&cnt[pk >> 17], 1);
    }
    __syncthreads();
    int v = cnt[t];
    excl[t] = v;
    __syncthreads();
    for (int s = 1; s < 256; s <<= 1) {
        int add = (t >= s) ? excl[t - s] : 0;
        __syncthreads();
        excl[t] += add;
        __syncthreads();
    }
    int mystart = excl[t] - v;  // exclusive start within bucket
    int node = b * NPB + t;
    if (node < N) {
        offsets[node] = bstart + mystart;
        deg[node] = v;
    }
    cnt[t] = mystart;           // reuse as placement cursor
    __syncthreads();
    for (int k = t; k < c; k += 256) {
        unsigned pk = tmp[bstart + k];
        int slot = atomicAdd(&cnt[pk >> 17], 1);
        col[bstart + slot] = (int)(pk & 0x1FFFFu);
    }
}

// ---- CSR gather + fused softmax denominator (round-5 proven form) --------
// One node per wave, grid (N+3)/4 — hardware dispatcher load-balances
// (round-6 lesson: 2048-block grid-stride killed backfill, 81->175us).
__global__ __launch_bounds__(256) void csr_gather(
        const int* __restrict__ offsets, const int* __restrict__ deg,
        const int* __restrict__ col, const float* __restrict__ a_src,
        const float* __restrict__ a_dst, const u16* __restrict__ xp,
        float* __restrict__ agg, int N) {
    int node = blockIdx.x * 4 + (threadIdx.x >> 6);
    if (node >= N) return;
    int lane  = threadIdx.x & 63;
    int h     = lane >> 4;          // head for channels 2*lane, 2*lane+1
    int q     = lane & 3;           // head this lane evaluates in chunk phase
    int esl   = lane >> 2;          // edge slot this lane evaluates
    int lane2 = lane << 1;          // u16 element offset into a row

    float ad_q = a_dst[node * NH + q];

    // self-loop (s == node)
    float w = __expf(lr(a_src[node * NH + h] + a_dst[node * NH + h]));
    unsigned xv = *(const unsigned*)(xp + (size_t)node * DH + lane2);
    float acc0 = w * b2f_lo(xv);
    float acc1 = w * b2f_hi(xv);
    float denv = 0.f;               // per-lane exp sum (own edge slot, head q)

    int off = offsets[node], dg = deg[node];
    const int* cp = col + off;

#define EDGE_F(K) {                                                       \
        float e = __shfl(ev, ((K) << 2) | h, 64);                         \
        int  su = __builtin_amdgcn_readlane(s_e, (K) << 2);               \
        const u16* row = xp + ((size_t)(unsigned)su << 7);                \
        unsigned v = *(const unsigned*)(row + lane2);                     \
        acc0 = fmaf(e, b2f_lo(v), acc0);                                  \
        acc1 = fmaf(e, b2f_hi(v), acc1); }

#define EDGE_P(K) {                                                       \
        float e = ((K) < rem) ? __shfl(ev, ((K) << 2) | h, 64) : 0.f;     \
        int  su = __builtin_amdgcn_readlane(s_e, (K) << 2);               \
        const u16* row = xp + ((size_t)(unsigned)su << 7);                \
        unsigned v = *(const unsigned*)(row + lane2);                     \
        acc0 = fmaf(e, b2f_lo(v), acc0);                                  \
        acc1 = fmaf(e, b2f_hi(v), acc1); }

    for (int k0 = 0; k0 < dg; k0 += 16) {
        int rem  = dg - k0;                       // > 0
        int kidx = min(k0 + esl, dg - 1);         // clamped slot
        int s_e  = cp[kidx];
        float ev = __expf(lr(a_src[s_e * NH + q] + ad_q));
        denv += ((k0 + esl) < dg) ? ev : 0.f;
        if (rem >= 16) {
            #pragma unroll
            for (int k = 0; k < 16; k++) EDGE_F(k)
        } else {
            #pragma unroll
            for (int k = 0; k < 16; k++) EDGE_P(k)
        }
    }
#undef EDGE_F
#undef EDGE_P

    // butterfly over lanes sharing q (xor bits 2..5), then pick head h's sum
    #pragma unroll
    for (int m = 4; m <= 32; m <<= 1)
        denv += __shfl_xor(denv, m, 64);
    float den = __shfl(denv, h, 64) + w;

    float inv = 1.0f / den;
    float2 o; o.x = acc0 * inv; o.y = acc1 * inv;
    *(float2*)(agg + (size_t)node * DH + lane2) = o;   // 512B/wave coalesced
}

// ---- BN stats pass 1: float4 rows, LDS tree, write partials (NO atomics)
// Round-8 diagnosis: same-address fp32 atomicAdd ~100ns serialized; 262K
// atomics over 256 addresses = ~106us. Partials to global instead.
__global__ __launch_bounds__(256) void stats_pass1(
        const float* __restrict__ agg, int N, float* __restrict__ partial) {
    int grp = threadIdx.x & 31;    // column quad: cols 4*grp .. 4*grp+3
    int sub = threadIdx.x >> 5;    // 0..7 row subgroup
    int c4  = grp << 2;
    floatx4 s1 = {0.f, 0.f, 0.f, 0.f}, s2 = {0.f, 0.f, 0.f, 0.f};
    int rpb = (N + gridDim.x - 1) / gridDim.x;
    int r0  = blockIdx.x * rpb;
    int r1  = min(N, r0 + rpb);
    for (int r = r0 + sub; r < r1; r += 8) {
        floatx4 v = *(const floatx4*)(agg + (size_t)r * DH + c4);
        s1 += v;
        s2 += v * v;
    }
    __shared__ floatx4 red1[8][32];
    __shared__ floatx4 red2[8][32];
    red1[sub][grp] = s1;
    red2[sub][grp] = s2;
    __syncthreads();
    for (int s = 4; s >= 1; s >>= 1) {
        if (sub < s) {
            red1[sub][grp] += red1[sub + s][grp];
            red2[sub][grp] += red2[sub + s][grp];
        }
        __syncthreads();
    }
    if (sub == 0) {
        float* pb = partial + (size_t)blockIdx.x * 256;
        *(floatx4*)(pb + c4)       = red1[0][grp];
        *(floatx4*)(pb + 128 + c4) = red2[0][grp];
    }
}

// ---- BN stats pass 2: reduce [512][256] partials, no atomics -------------
// 2 blocks x 1024 threads (block 0 -> colsum, block 1 -> colsumsq); 8 loads
// in flight per thread (round-3's 1-block rolled pass2 was 120us).
__global__ __launch_bounds__(1024) void stats_pass2(
        const float* __restrict__ partial,
        float* __restrict__ colsum, float* __restrict__ colsumsq) {
    int which = blockIdx.x;           // 0: sum, 1: sumsq
    int c   = threadIdx.x & 127;      // column
    int seg = threadIdx.x >> 7;       // 0..7, 64 partial-rows each
    const float* base = partial + which * 128 + c;
    float acc = 0.f;
    int b0 = seg * 64;
    #pragma unroll 8
    for (int b = b0; b < b0 + 64; b++)
        acc += base[(size_t)b * 256];
    __shared__ float red[8][128];
    red[seg][c] = acc;
    __syncthreads();
    if (seg == 0) {
        float s = red[0][c] + red[1][c] + red[2][c] + red[3][c]
                + red[4][c] + red[5][c] + red[6][c] + red[7][c];
        if (which == 0) colsum[c] = s; else colsumsq[c] = s;
    }
}

// ---- BN normalize + ELU + residual (float4, 1 pass) ----------------------
// gat_bias cancels exactly in training-mode BN (shifts column mean only)
__global__ __launch_bounds__(256) void final_kernel(
        const float* __restrict__ agg, const float* __restrict__ colsum,
        const float* __restrict__ colsumsq, const float* __restrict__ gamma,
        const float* __restrict__ beta, float* __restrict__ out, int N) {
    int t = blockIdx.x * blockDim.x + threadIdx.x;   // over N * (DH/4)
    if (t >= N * (DH / 4)) return;
    int row = t >> 5;                 // DH/4 = 32 float4 per row
    int c4  = (t & 31) << 2;
    float inv_n = 1.0f / (float)N;

    floatx4 s1 = *(const floatx4*)(colsum   + c4);
    floatx4 s2 = *(const floatx4*)(colsumsq + c4);
    floatx4 g  = *(const floatx4*)(gamma    + c4);
    floatx4 b  = *(const floatx4*)(beta     + c4);
    floatx4 a  = *(const floatx4*)(agg + (size_t)row * DH + c4);
    floatx4 o  = *(const floatx4*)(out + (size_t)row * DH + c4);

    #pragma unroll
    for (int j = 0; j < 4; j++) {
        float mu   = s1[j] * inv_n;
        float var  = s2[j] * inv_n - mu * mu;
        float rstd = rsqrtf(var + 1e-5f);
        float v = (a[j] - mu) * rstd * g[j] + b[j];
        v = v > 0.f ? v : (__expf(v) - 1.f);          // ELU(alpha=1)
        float r = o[j] + v;                            // + h_in (in d_out)
        if (!(r >= -1e30f && r <= 1e30f)) r = 512.0f;  // tripwire sentinel
        o[j] = r;
    }
    *(floatx4*)(out + (size_t)row * DH + c4) = o;
}

extern "C" void kernel_launch(void* const* d_in, const int* in_sizes, int n_in,
                              void* d_out, int out_size, void* d_ws, size_t ws_size,
                              hipStream_t stream) {
    const float* x        = (const float*)d_in[0];
    const int*   ei       = (const int*)d_in[1];
    const float* lin_w    = (const float*)d_in[2];
    const float* lin_b    = (const float*)d_in[3];
    const float* gat_w    = (const float*)d_in[4];
    const float* att_src  = (const float*)d_in[5];
    const float* att_dst  = (const float*)d_in[6];
    // d_in[7] gat_bias: cancels in training-mode BN — unused
    const float* bn_gamma = (const float*)d_in[8];
    const float* bn_beta  = (const float*)d_in[9];

    int N = in_sizes[0] / DH;
    int E = in_sizes[1] / 2;
    int B = (N + NPB - 1) / NPB;          // buckets (<=512 for N<=131072)
    int EB = (E + EPB - 1) / EPB;         // binning blocks

    // ---- ws carve (16B aligned) ----
    char* p = (char*)d_ws;
    u16*   xp      = (u16*)p;        p += (size_t)N * DH * 2;   // 25.6 MB
    float* a_src   = (float*)p;      p += (size_t)N * NH * 4;
    float* a_dst   = (float*)p;      p += (size_t)N * NH * 4;
    u16*   wpack   = (u16*)p;        p += 32768 * 2;
    int*   col     = (int*)p;        p += (size_t)E * 4;        //  6.4 MB
    int*   offsets = (int*)p;        p += (size_t)N * 4;
    int*   deg     = (int*)p;        p += (size_t)N * 4;
    int*   bbase   = (int*)p;        p += MAXB * 4;
    int*   bcur    = (int*)p;        p += MAXB * 4;
    float* partial = (float*)p;      p += (size_t)SGRID * 256 * 4;  // 512 KB
    char* zero_begin = p;
    int*   bcount  = (int*)p;        p += MAXB * 4;
    float* colsum  = (float*)p;      p += DH * 4;
    float* colsumsq= (float*)p;      p += DH * 4;
    size_t zero_bytes = (size_t)(p - zero_begin);
    float* agg     = (float*)p;      // N*DH fp32 (51.2 MB; fits — proven)
    unsigned* tmp  = (unsigned*)agg; // aliased: tmp dead before agg written

    hipMemsetAsync(zero_begin, 0, zero_bytes, stream);

    repack_w<<<(16 * 4 * 64 * 8) / 256, 256, 0, stream>>>(lin_w, gat_w, wpack);

    gemm_mfma<<<(N + 127) / 128, 512, 0, stream>>>(x, lin_b, wpack, att_src,
                                                   att_dst, (float*)d_out, xp,
                                                   a_src, a_dst, N);

    // CSR build v2 (bucketed, LDS-staged)
    bucket_count<<<EB, 256, 0, stream>>>(ei, E, N, B, bcount);
    bucket_scan<<<1, 512, 0, stream>>>(bcount, B, bbase, bcur);
    bucket_scatter<<<EB, 256, 0, stream>>>(ei, E, N, B, bcur, tmp);
    bucket_to_csr<<<B, 256, 0, stream>>>(tmp, bbase, bcount, N,
                                         offsets, deg, col);

    csr_gather<<<(N + 3) / 4, 256, 0, stream>>>(offsets, deg, col, a_src,
                                                a_dst, xp, agg, N);
    stats_pass1<<<SGRID, 256, 0, stream>>>(agg, N, partial);
    stats_pass2<<<2, 1024, 0, stream>>>(partial, colsum, colsumsq);
    final_kernel<<<(N * (DH / 4) + 255) / 256, 256, 0, stream>>>(
        agg, colsum, colsumsq, bn_gamma, bn_beta, (float*)d_out, N);
}

// Round 11
// 316.378 us; speedup vs baseline: 1.3124x; 1.0105x over previous
//
#include <hip/hip_runtime.h>
#include <stdint.h>

typedef unsigned short u16;
typedef __attribute__((ext_vector_type(8))) short short8;
typedef __attribute__((ext_vector_type(4))) float floatx4;

#define DH 128   // D = H*C
#define NH 4     // heads
#define CH 32    // channels per head

#define NPB  256   // nodes per bucket (dst >> 8) — dlocal fits 8 bits
#define MAXB 512   // max buckets (N <= 131072)
#define EPB 8192   // edges per block in binning passes
#define SGRID 512  // stats pass-1 blocks (pass2 assumes exactly 512)

__device__ __forceinline__ float bf2f(u16 u) {
    union { unsigned int i; float f; } c; c.i = ((unsigned int)u) << 16; return c.f;
}
__device__ __forceinline__ u16 f2bf(float f) {
    union { float f; unsigned int i; } c; c.f = f;
    unsigned int x = c.i;
    x += 0x7FFFu + ((x >> 16) & 1u);   // round-to-nearest-even
    return (u16)(x >> 16);
}
// unpack a u32 holding two bf16 (lo = even channel, hi = odd channel)
__device__ __forceinline__ float b2f_lo(unsigned v) {
    union { unsigned u; float f; } c; c.u = v << 16; return c.f;
}
__device__ __forceinline__ float b2f_hi(unsigned v) {
    union { unsigned u; float f; } c; c.u = v & 0xffff0000u; return c.f;
}
// leaky_relu(x,0.2) branchless
__device__ __forceinline__ float lr(float x) { return fmaxf(x, 0.2f * x); }

// ---- repack [lin_w | gat_w] (f32) into MFMA B-fragment order (bf16) ------
__global__ void repack_w(const float* __restrict__ lin_w, const float* __restrict__ gat_w,
                         u16* __restrict__ wpack) {
    int t = blockIdx.x * blockDim.x + threadIdx.x;   // 0 .. 32767
    int j    = t & 7;
    int lane = (t >> 3) & 63;
    int ks   = (t >> 9) & 3;
    int ct   = t >> 11;
    int k    = ks * 32 + (lane >> 4) * 8 + j;
    int col  = ct * 16 + (lane & 15);
    float v = (col < DH) ? lin_w[k * DH + col] : gat_w[k * DH + (col - DH)];
    wpack[t] = f2bf(v);
}

// ---- MFMA GEMM + fused attention logits, LDS-staged B --------------------
// Block stages wpack into LDS once (coalesced float4); B-fragments from
// ds_read_b128 (no L1 thrash). 512 thr/block (8 waves, 128 rows); 64KB LDS.
__global__ __launch_bounds__(512) void gemm_mfma(
        const float* __restrict__ x, const float* __restrict__ lin_b,
        const u16* __restrict__ wpack, const float* __restrict__ att_src,
        const float* __restrict__ att_dst, float* __restrict__ h_out,
        u16* __restrict__ xp, float* __restrict__ a_src,
        float* __restrict__ a_dst, int N) {
    __shared__ u16 wlds[32768];   // 64 KB
    {
        float4* dstv = (float4*)wlds;
        const float4* srcv = (const float4*)wpack;
        #pragma unroll
        for (int i = 0; i < 8; i++)
            dstv[threadIdx.x + i * 512] = srcv[threadIdx.x + i * 512];
    }
    __syncthreads();

    int wave = threadIdx.x >> 6;
    int lane = threadIdx.x & 63;
    int rowBase = blockIdx.x * 128 + wave * 16;
    if (rowBase >= N) return;
    int m = lane & 15, quad = lane >> 4;

    short8 afr[4];
    const float* xrow = x + (size_t)(rowBase + m) * DH + quad * 8;
    #pragma unroll
    for (int ks = 0; ks < 4; ks++) {
        float4 f0 = *(const float4*)(xrow + ks * 32);
        float4 f1 = *(const float4*)(xrow + ks * 32 + 4);
        short8 a;
        a[0] = (short)f2bf(f0.x); a[1] = (short)f2bf(f0.y);
        a[2] = (short)f2bf(f0.z); a[3] = (short)f2bf(f0.w);
        a[4] = (short)f2bf(f1.x); a[5] = (short)f2bf(f1.y);
        a[6] = (short)f2bf(f1.z); a[7] = (short)f2bf(f1.w);
        afr[ks] = a;
    }

    // ---- first half: h_in columns 0..127 ----
    #pragma unroll 4
    for (int ct = 0; ct < 8; ct++) {
        floatx4 acc = {0.f, 0.f, 0.f, 0.f};
        const short8* bp = (const short8*)wlds + (ct * 4) * 64 + lane;
        #pragma unroll
        for (int ks = 0; ks < 4; ks++) {
            short8 bfr = bp[ks * 64];
            acc = __builtin_amdgcn_mfma_f32_16x16x32_bf16(afr[ks], bfr, acc, 0, 0, 0);
        }
        int col = ct * 16 + m;   // D: col=lane&15, row=quad*4+r
        float bias = lin_b[col];
        #pragma unroll
        for (int r = 0; r < 4; r++)
            h_out[(size_t)(rowBase + quad * 4 + r) * DH + col] = acc[r] + bias;
    }

    // ---- second half: xp columns + fused per-head logits ----
    float pS[4], pD[4];
    #pragma unroll
    for (int ct2 = 0; ct2 < 8; ct2++) {
        const int ct = ct2 + 8;
        const int hh = ct2 >> 1;          // head, compile-time
        floatx4 acc = {0.f, 0.f, 0.f, 0.f};
        const short8* bp = (const short8*)wlds + (ct * 4) * 64 + lane;
        #pragma unroll
        for (int ks = 0; ks < 4; ks++) {
            short8 bfr = bp[ks * 64];
            acc = __builtin_amdgcn_mfma_f32_16x16x32_bf16(afr[ks], bfr, acc, 0, 0, 0);
        }
        int c2 = ct2 * 16 + m;            // xp column
        #pragma unroll
        for (int r = 0; r < 4; r++)
            xp[(size_t)(rowBase + quad * 4 + r) * DH + c2] = f2bf(acc[r]);

        // logit partials: within head hh, this ct covers channel
        // (ct2&1)*16 + m of that head
        int ch = ((ct2 & 1) << 4) + m;
        float ws = att_src[hh * CH + ch];
        float wd = att_dst[hh * CH + ch];
        if (!(ct2 & 1)) {
            #pragma unroll
            for (int r = 0; r < 4; r++) { pS[r] = acc[r] * ws; pD[r] = acc[r] * wd; }
        } else {
            #pragma unroll
            for (int r = 0; r < 4; r++) {
                pS[r] = fmaf(acc[r], ws, pS[r]);
                pD[r] = fmaf(acc[r], wd, pD[r]);
            }
            // reduce over the 16 m-lanes (lane bits 0..3)
            #pragma unroll
            for (int r = 0; r < 4; r++) {
                #pragma unroll
                for (int mk = 1; mk <= 8; mk <<= 1) {
                    pS[r] += __shfl_xor(pS[r], mk, 64);
                    pD[r] += __shfl_xor(pD[r], mk, 64);
                }
            }
            if (m == 0) {
                #pragma unroll
                for (int r = 0; r < 4; r++) {
                    int node = rowBase + quad * 4 + r;
                    a_src[node * NH + hh] = pS[r];
                    a_dst[node * NH + hh] = pD[r];
                }
            }
        }
    }
}

// ==================== CSR build v2: two-level bucket sort ====================

// ---- pass 1: bucket histogram (LDS hist, one atomic per block-bucket) ----
__global__ __launch_bounds__(256) void bucket_count(
        const int* __restrict__ ei, int E, int N, int B,
        int* __restrict__ bcount) {
    __shared__ int h[MAXB];
    for (int j = threadIdx.x; j < B; j += 256) h[j] = 0;
    __syncthreads();
    int i0 = blockIdx.x * EPB;
    int i1 = min(E, i0 + EPB);
    for (int i = i0 + threadIdx.x; i < i1; i += 256) {
        int d = min(max(ei[E + i], 0), N - 1);
        atomicAdd(&h[d >> 8], 1);
    }
    __syncthreads();
    for (int j = threadIdx.x; j < B; j += 256) {
        int c = h[j];
        if (c) atomicAdd(&bcount[j], c);
    }
}

// ---- pass 2: exclusive scan of bucket sizes; init claim cursors ----------
__global__ __launch_bounds__(512) void bucket_scan(
        const int* __restrict__ bcount, int B,
        int* __restrict__ bbase, int* __restrict__ bcur) {
    __shared__ int buf[512];
    int t = threadIdx.x;
    int v = (t < B) ? bcount[t] : 0;
    buf[t] = v;
    __syncthreads();
    for (int s = 1; s < 512; s <<= 1) {
        int add = (t >= s) ? buf[t - s] : 0;
        __syncthreads();
        buf[t] += add;
        __syncthreads();
    }
    if (t < B) { int e = buf[t] - v; bbase[t] = e; bcur[t] = e; }
}

// ---- pass 3: scatter edges into bucket segments (packed src|dlocal) ------
__global__ __launch_bounds__(256) void bucket_scatter(
        const int* __restrict__ ei, int E, int N, int B,
        int* __restrict__ bcur, unsigned* __restrict__ tmp) {
    __shared__ int h[MAXB];     // histogram, then LDS cursor
    __shared__ int base[MAXB];  // global base claimed for this block
    for (int j = threadIdx.x; j < B; j += 256) h[j] = 0;
    __syncthreads();
    int i0 = blockIdx.x * EPB;
    int i1 = min(E, i0 + EPB);
    for (int i = i0 + threadIdx.x; i < i1; i += 256) {
        int d = min(max(ei[E + i], 0), N - 1);
        atomicAdd(&h[d >> 8], 1);
    }
    __syncthreads();
    for (int j = threadIdx.x; j < B; j += 256) {
        int c = h[j];
        base[j] = c ? atomicAdd(&bcur[j], c) : 0;
    }
    __syncthreads();
    for (int j = threadIdx.x; j < B; j += 256) h[j] = 0;  // reuse as cursor
    __syncthreads();
    for (int i = i0 + threadIdx.x; i < i1; i += 256) {
        int s = min(max(ei[i], 0), N - 1);
        int d = min(max(ei[E + i], 0), N - 1);
        int b = d >> 8;
        int pos = base[b] + atomicAdd(&h[b], 1);
        tmp[pos] = (unsigned)s | ((unsigned)(d & 255) << 17);   // N<=131072
    }
}

// ---- pass 4: per-bucket LDS counting sort -> col, deg, offsets -----------
__global__ __launch_bounds__(256) void bucket_to_csr(
        const unsigned* __restrict__ tmp, const int* __restrict__ bbase,
        const int* __restrict__ bcount, int N,
        int* __restrict__ offsets, int* __restrict__ deg,
        int* __restrict__ col) {
    __shared__ int cnt[NPB];    // per-node count, then LDS cursor
    __shared__ int excl[NPB];
    int b = blockIdx.x;
    int t = threadIdx.x;        // 256 threads == NPB
    int bstart = bbase[b];
    int c = bcount[b];
    cnt[t] = 0;
    __syncthreads();
    for (int k = t; k < c; k += 256) {
        unsigned pk = tmp[bstart + k];
        atomicAdd(&cnt[pk >> 17], 1);
    }
    __syncthreads();
    int v = cnt[t];
    excl[t] = v;
    __syncthreads();
    for (int s = 1; s < 256; s <<= 1) {
        int add = (t >= s) ? excl[t - s] : 0;
        __syncthreads();
        excl[t] += add;
        __syncthreads();
    }
    int mystart = excl[t] - v;  // exclusive start within bucket
    int node = b * NPB + t;
    if (node < N) {
        offsets[node] = bstart + mystart;
        deg[node] = v;
    }
    cnt[t] = mystart;           // reuse as placement cursor
    __syncthreads();
    for (int k = t; k < c; k += 256) {
        unsigned pk = tmp[bstart + k];
        int slot = atomicAdd(&cnt[pk >> 17], 1);
        col[bstart + slot] = (int)(pk & 0x1FFFFu);
    }
}

// ---- CSR gather + fused softmax denominator ------------------------------
// One node per wave, grid (N+3)/4 (dispatcher load-balances; round-6 lesson).
// Round-11: Duff's-device tail — rem is WAVE-UNIFORM, so a switch over
// 4-edge groups executes only ceil(rem/4)*4 edge bodies instead of all 16.
// Mean deg 16.4 meant ~8 wasted (clamped same-line) loads + fmas per node
// = ~25% of issue slots; now ~1.7.
__global__ __launch_bounds__(256) void csr_gather(
        const int* __restrict__ offsets, const int* __restrict__ deg,
        const int* __restrict__ col, const float* __restrict__ a_src,
        const float* __restrict__ a_dst, const u16* __restrict__ xp,
        float* __restrict__ agg, int N) {
    int node = blockIdx.x * 4 + (threadIdx.x >> 6);
    if (node >= N) return;
    int lane  = threadIdx.x & 63;
    int h     = lane >> 4;          // head for channels 2*lane, 2*lane+1
    int q     = lane & 3;           // head this lane evaluates in chunk phase
    int esl   = lane >> 2;          // edge slot this lane evaluates
    int lane2 = lane << 1;          // u16 element offset into a row

    float ad_q = a_dst[node * NH + q];

    // self-loop (s == node)
    float w = __expf(lr(a_src[node * NH + h] + a_dst[node * NH + h]));
    unsigned xv = *(const unsigned*)(xp + (size_t)node * DH + lane2);
    float acc0 = w * b2f_lo(xv);
    float acc1 = w * b2f_hi(xv);
    float denv = 0.f;               // per-lane exp sum (own edge slot, head q)

    int off = offsets[node], dg = deg[node];
    const int* cp = col + off;

#define EDGE_F(K) {                                                       \
        float e = __shfl(ev, ((K) << 2) | h, 64);                         \
        int  su = __builtin_amdgcn_readlane(s_e, (K) << 2);               \
        const u16* row = xp + ((size_t)(unsigned)su << 7);                \
        unsigned v = *(const unsigned*)(row + lane2);                     \
        acc0 = fmaf(e, b2f_lo(v), acc0);                                  \
        acc1 = fmaf(e, b2f_hi(v), acc1); }

#define EDGE_P(K) {                                                       \
        float e = ((K) < rem) ? __shfl(ev, ((K) << 2) | h, 64) : 0.f;     \
        int  su = __builtin_amdgcn_readlane(s_e, (K) << 2);               \
        const u16* row = xp + ((size_t)(unsigned)su << 7);                \
        unsigned v = *(const unsigned*)(row + lane2);                     \
        acc0 = fmaf(e, b2f_lo(v), acc0);                                  \
        acc1 = fmaf(e, b2f_hi(v), acc1); }

    int k0 = 0;
    for (; k0 + 16 <= dg; k0 += 16) {
        int   s_e = cp[k0 + esl];
        float ev  = __expf(lr(a_src[s_e * NH + q] + ad_q));
        denv += ev;                       // all 16 slots valid in full chunk
        #pragma unroll
        for (int k = 0; k < 16; k++) EDGE_F(k)
    }
    int rem = dg - k0;                    // 0..15, wave-uniform
    if (rem) {
        int kidx = min(k0 + esl, dg - 1); // clamped slot
        int   s_e = cp[kidx];
        float ev  = __expf(lr(a_src[s_e * NH + q] + ad_q));
        denv += ((k0 + esl) < dg) ? ev : 0.f;
        switch ((rem + 3) >> 2) {         // 1..4 groups of 4 (order-free sum)
            case 4: EDGE_P(15) EDGE_P(14) EDGE_P(13) EDGE_P(12) [[fallthrough]];
            case 3: EDGE_P(11) EDGE_P(10) EDGE_P(9)  EDGE_P(8)  [[fallthrough]];
            case 2: EDGE_P(7)  EDGE_P(6)  EDGE_P(5)  EDGE_P(4)  [[fallthrough]];
            case 1: EDGE_P(3)  EDGE_P(2)  EDGE_P(1)  EDGE_P(0);
        }
    }
#undef EDGE_F
#undef EDGE_P

    // butterfly over lanes sharing q (xor bits 2..5), then pick head h's sum
    #pragma unroll
    for (int m = 4; m <= 32; m <<= 1)
        denv += __shfl_xor(denv, m, 64);
    float den = __shfl(denv, h, 64) + w;

    float inv = 1.0f / den;
    float2 o; o.x = acc0 * inv; o.y = acc1 * inv;
    *(float2*)(agg + (size_t)node * DH + lane2) = o;   // 512B/wave coalesced
}

// ---- BN stats pass 1: float4 rows, LDS tree, write partials (NO atomics)
// Round-8 diagnosis: same-address fp32 atomicAdd ~100ns serialized; 262K
// atomics over 256 addresses = ~106us. Partials to global instead.
__global__ __launch_bounds__(256) void stats_pass1(
        const float* __restrict__ agg, int N, float* __restrict__ partial) {
    int grp = threadIdx.x & 31;    // column quad: cols 4*grp .. 4*grp+3
    int sub = threadIdx.x >> 5;    // 0..7 row subgroup
    int c4  = grp << 2;
    floatx4 s1 = {0.f, 0.f, 0.f, 0.f}, s2 = {0.f, 0.f, 0.f, 0.f};
    int rpb = (N + gridDim.x - 1) / gridDim.x;
    int r0  = blockIdx.x * rpb;
    int r1  = min(N, r0 + rpb);
    for (int r = r0 + sub; r < r1; r += 8) {
        floatx4 v = *(const floatx4*)(agg + (size_t)r * DH + c4);
        s1 += v;
        s2 += v * v;
    }
    __shared__ floatx4 red1[8][32];
    __shared__ floatx4 red2[8][32];
    red1[sub][grp] = s1;
    red2[sub][grp] = s2;
    __syncthreads();
    for (int s = 4; s >= 1; s >>= 1) {
        if (sub < s) {
            red1[sub][grp] += red1[sub + s][grp];
            red2[sub][grp] += red2[sub + s][grp];
        }
        __syncthreads();
    }
    if (sub == 0) {
        float* pb = partial + (size_t)blockIdx.x * 256;
        *(floatx4*)(pb + c4)       = red1[0][grp];
        *(floatx4*)(pb + 128 + c4) = red2[0][grp];
    }
}

// ---- BN stats pass 2: reduce [512][256] partials, no atomics -------------
// 2 blocks x 1024 threads (block 0 -> colsum, block 1 -> colsumsq); 8 loads
// in flight per thread (round-3's 1-block rolled pass2 was 120us).
__global__ __launch_bounds__(1024) void stats_pass2(
        const float* __restrict__ partial,
        float* __restrict__ colsum, float* __restrict__ colsumsq) {
    int which = blockIdx.x;           // 0: sum, 1: sumsq
    int c   = threadIdx.x & 127;      // column
    int seg = threadIdx.x >> 7;       // 0..7, 64 partial-rows each
    const float* base = partial + which * 128 + c;
    float acc = 0.f;
    int b0 = seg * 64;
    #pragma unroll 8
    for (int b = b0; b < b0 + 64; b++)
        acc += base[(size_t)b * 256];
    __shared__ float red[8][128];
    red[seg][c] = acc;
    __syncthreads();
    if (seg == 0) {
        float s = red[0][c] + red[1][c] + red[2][c] + red[3][c]
                + red[4][c] + red[5][c] + red[6][c] + red[7][c];
        if (which == 0) colsum[c] = s; else colsumsq[c] = s;
    }
}

// ---- BN normalize + ELU + residual (float4, 1 pass) ----------------------
// gat_bias cancels exactly in training-mode BN (shifts column mean only)
__global__ __launch_bounds__(256) void final_kernel(
        const float* __restrict__ agg, const float* __restrict__ colsum,
        const float* __restrict__ colsumsq, const float* __restrict__ gamma,
        const float* __restrict__ beta, float* __restrict__ out, int N) {
    int t = blockIdx.x * blockDim.x + threadIdx.x;   // over N * (DH/4)
    if (t >= N * (DH / 4)) return;
    int row = t >> 5;                 // DH/4 = 32 float4 per row
    int c4  = (t & 31) << 2;
    float inv_n = 1.0f / (float)N;

    floatx4 s1 = *(const floatx4*)(colsum   + c4);
    floatx4 s2 = *(const floatx4*)(colsumsq + c4);
    floatx4 g  = *(const floatx4*)(gamma    + c4);
    floatx4 b  = *(const floatx4*)(beta     + c4);
    floatx4 a  = *(const floatx4*)(agg + (size_t)row * DH + c4);
    floatx4 o  = *(const floatx4*)(out + (size_t)row * DH + c4);

    #pragma unroll
    for (int j = 0; j < 4; j++) {
        float mu   = s1[j] * inv_n;
        float var  = s2[j] * inv_n - mu * mu;
        float rstd = rsqrtf(var + 1e-5f);
        float v = (a[j] - mu) * rstd * g[j] + b[j];
        v = v > 0.f ? v : (__expf(v) - 1.f);          // ELU(alpha=1)
        float r = o[j] + v;                            // + h_in (in d_out)
        if (!(r >= -1e30f && r <= 1e30f)) r = 512.0f;  // tripwire sentinel
        o[j] = r;
    }
    *(floatx4*)(out + (size_t)row * DH + c4) = o;
}

extern "C" void kernel_launch(void* const* d_in, const int* in_sizes, int n_in,
                              void* d_out, int out_size, void* d_ws, size_t ws_size,
                              hipStream_t stream) {
    const float* x        = (const float*)d_in[0];
    const int*   ei       = (const int*)d_in[1];
    const float* lin_w    = (const float*)d_in[2];
    const float* lin_b    = (const float*)d_in[3];
    const float* gat_w    = (const float*)d_in[4];
    const float* att_src  = (const float*)d_in[5];
    const float* att_dst  = (const float*)d_in[6];
    // d_in[7] gat_bias: cancels in training-mode BN — unused
    const float* bn_gamma = (const float*)d_in[8];
    const float* bn_beta  = (const float*)d_in[9];

    int N = in_sizes[0] / DH;
    int E = in_sizes[1] / 2;
    int B = (N + NPB - 1) / NPB;          // buckets (<=512 for N<=131072)
    int EB = (E + EPB - 1) / EPB;         // binning blocks

    // ---- ws carve (16B aligned) ----
    char* p = (char*)d_ws;
    u16*   xp      = (u16*)p;        p += (size_t)N * DH * 2;   // 25.6 MB
    float* a_src   = (float*)p;      p += (size_t)N * NH * 4;
    float* a_dst   = (float*)p;      p += (size_t)N * NH * 4;
    u16*   wpack   = (u16*)p;        p += 32768 * 2;
    int*   col     = (int*)p;        p += (size_t)E * 4;        //  6.4 MB
    int*   offsets = (int*)p;        p += (size_t)N * 4;
    int*   deg     = (int*)p;        p += (size_t)N * 4;
    int*   bbase   = (int*)p;        p += MAXB * 4;
    int*   bcur    = (int*)p;        p += MAXB * 4;
    float* partial = (float*)p;      p += (size_t)SGRID * 256 * 4;  // 512 KB
    char* zero_begin = p;
    int*   bcount  = (int*)p;        p += MAXB * 4;
    float* colsum  = (float*)p;      p += DH * 4;
    float* colsumsq= (float*)p;      p += DH * 4;
    size_t zero_bytes = (size_t)(p - zero_begin);
    float* agg     = (float*)p;      // N*DH fp32 (51.2 MB; fits — proven)
    unsigned* tmp  = (unsigned*)agg; // aliased: tmp dead before agg written

    hipMemsetAsync(zero_begin, 0, zero_bytes, stream);

    repack_w<<<(16 * 4 * 64 * 8) / 256, 256, 0, stream>>>(lin_w, gat_w, wpack);

    gemm_mfma<<<(N + 127) / 128, 512, 0, stream>>>(x, lin_b, wpack, att_src,
                                                   att_dst, (float*)d_out, xp,
                                                   a_src, a_dst, N);

    // CSR build v2 (bucketed, LDS-staged)
    bucket_count<<<EB, 256, 0, stream>>>(ei, E, N, B, bcount);
    bucket_scan<<<1, 512, 0, stream>>>(bcount, B, bbase, bcur);
    bucket_scatter<<<EB, 256, 0, stream>>>(ei, E, N, B, bcur, tmp);
    bucket_to_csr<<<B, 256, 0, stream>>>(tmp, bbase, bcount, N,
                                         offsets, deg, col);

    csr_gather<<<(N + 3) / 4, 256, 0, stream>>>(offsets, deg, col, a_src,
                                                a_dst, xp, agg, N);
    stats_pass1<<<SGRID, 256, 0, stream>>>(agg, N, partial);
    stats_pass2<<<2, 1024, 0, stream>>>(partial, colsum, colsumsq);
    final_kernel<<<(N * (DH / 4) + 255) / 256, 256, 0, stream>>>(
        agg, colsum, colsumsq, bn_gamma, bn_beta, (float*)d_out, N);
}